// Round 4
// baseline (545.664 us; speedup 1.0000x reference)
//
#include <hip/hip_runtime.h>

#define HB 32
#define HT 256
#define HC 2048
#define HH 16
#define HD 128
#define HM (HB * HT)  // 8192

typedef __bf16 bf16x8 __attribute__((ext_vector_type(8)));
typedef float f32x4 __attribute__((ext_vector_type(4)));
typedef float f32x16 __attribute__((ext_vector_type(16)));

__device__ __forceinline__ unsigned short f2bf(float f) {
  unsigned u = __float_as_uint(f);
  u += 0x7FFFu + ((u >> 16) & 1u);  // round-to-nearest-even
  return (unsigned short)(u >> 16);
}
__device__ __forceinline__ float bf2f(unsigned short h) {
  return __uint_as_float(((unsigned)h) << 16);
}

// ---------------- fused fp32 -> bf16 convert (x + 4 weights) ----------------
__global__ __launch_bounds__(256) void cvt_all(
    const float* __restrict__ x, const float* __restrict__ wq, const float* __restrict__ wk,
    const float* __restrict__ wv, const float* __restrict__ wo,
    unsigned short* __restrict__ xb, unsigned short* __restrict__ wqb,
    unsigned short* __restrict__ wkb, unsigned short* __restrict__ wvb,
    unsigned short* __restrict__ wob) {
  size_t i = (size_t)blockIdx.x * 256 + threadIdx.x;
  const float* src;
  unsigned short* dst;
  size_t off;
  if (i < 4194304) {
    src = x; dst = xb; off = i;
  } else {
    size_t j = i - 4194304;
    int w = (int)(j >> 20);
    off = j & 1048575;
    src = (w == 0) ? wq : (w == 1) ? wk : (w == 2) ? wv : wo;
    dst = (w == 0) ? wqb : (w == 1) ? wkb : (w == 2) ? wvb : wob;
  }
  float4 v = ((const float4*)src)[off];
  ushort4 o;
  o.x = f2bf(v.x); o.y = f2bf(v.y); o.z = f2bf(v.z); o.w = f2bf(v.w);
  ((ushort4*)dst)[off] = o;
}

// ---------------- GEMM core: 128x128 tile, BK=64, 32x32x16 MFMA ----------------
__device__ __forceinline__ void gl_lds16(const unsigned short* g, unsigned short* l) {
  __builtin_amdgcn_global_load_lds((const __attribute__((address_space(1))) void*)g,
                                   (__attribute__((address_space(3))) void*)l, 16, 0, 0);
}

// Wave output: rows wr*64 + mi*32 + l31, cols nj*64 + wc*32 + l31 (nj splits the
// 128-col tile into two 64-halves so RoPE pairs (d, d+64) share a lane/reg).
__device__ __forceinline__ void gemm_core32(const unsigned short* __restrict__ Ab,
                                            const unsigned short* __restrict__ Wb,
                                            unsigned short* lsA, unsigned short* lsB,
                                            f32x16 acc[2][2], int tid) {
  const int lane = tid & 63, wave = tid >> 6;
  const int l31 = lane & 31, half = lane >> 5;
  const int wr = wave >> 1, wc = wave & 1;
  for (int kt = 0; kt < HC / 64; ++kt) {
    __syncthreads();
#pragma unroll
    for (int i = 0; i < 4; i++) {
      int c = i * 256 + tid;
      int row = c >> 3, cc = c & 7;
      int gc = cc ^ (row & 7);
      gl_lds16(Ab + (size_t)row * HC + kt * 64 + gc * 8, lsA + c * 8);
      gl_lds16(Wb + (size_t)row * HC + kt * 64 + gc * 8, lsB + c * 8);
    }
    __syncthreads();
#pragma unroll
    for (int ks = 0; ks < 4; ++ks) {
      const int g = ks * 2 + half;
      bf16x8 af[2], bfr[2];
#pragma unroll
      for (int mi = 0; mi < 2; mi++) {
        int r = wr * 64 + mi * 32 + l31;
        int cc = g ^ (r & 7);
        af[mi] = *(const bf16x8*)(lsA + r * 64 + cc * 8);
      }
#pragma unroll
      for (int nj = 0; nj < 2; nj++) {
        int r = nj * 64 + wc * 32 + l31;
        int cc = g ^ (r & 7);
        bfr[nj] = *(const bf16x8*)(lsB + r * 64 + cc * 8);
      }
#pragma unroll
      for (int mi = 0; mi < 2; mi++)
#pragma unroll
        for (int nj = 0; nj < 2; nj++)
          acc[mi][nj] = __builtin_amdgcn_mfma_f32_32x32x16_bf16(af[mi], bfr[nj], acc[mi][nj], 0, 0, 0);
    }
  }
}

// Output projection GEMM: fp32 out [M, 2048]
__global__ __launch_bounds__(256) void gemm_out(const unsigned short* __restrict__ A,
                                                const unsigned short* __restrict__ W,
                                                float* __restrict__ outp) {
  __shared__ __align__(16) unsigned short lsA[128 * 64];
  __shared__ __align__(16) unsigned short lsB[128 * 64];
  const int tid = threadIdx.x;
  const int lane = tid & 63, wave = tid >> 6;
  const int l31 = lane & 31, half = lane >> 5;
  const int wr = wave >> 1, wc = wave & 1;
  const int bm = blockIdx.x, bn = blockIdx.y;

  f32x16 acc[2][2];
#pragma unroll
  for (int i = 0; i < 2; i++)
#pragma unroll
    for (int j = 0; j < 2; j++)
#pragma unroll
      for (int r = 0; r < 16; r++) acc[i][j][r] = 0.f;

  gemm_core32(A + (size_t)bm * 128 * HC, W + (size_t)bn * 128 * HC, lsA, lsB, acc, tid);

#pragma unroll
  for (int mi = 0; mi < 2; mi++)
#pragma unroll
    for (int nj = 0; nj < 2; nj++)
#pragma unroll
      for (int g = 0; g < 4; g++)
#pragma unroll
        for (int rr = 0; rr < 4; rr++) {
          int m = bm * 128 + wr * 64 + mi * 32 + rr + 8 * g + 4 * half;
          int n = bn * 128 + nj * 64 + wc * 32 + l31;
          outp[(size_t)m * HC + n] = acc[mi][nj][g * 4 + rr];
        }
}

// Fused QKV GEMM: grid (64, 48); blockIdx.y>>4 selects {Q,K,V}.
// Q,K -> [B,H,T,D] with RoPE fused; V -> [B,H,D,T] via operand swap (coalesced).
__global__ __launch_bounds__(256) void gemm_qkv(const unsigned short* __restrict__ A,
                                                const unsigned short* __restrict__ W0,
                                                const unsigned short* __restrict__ W1,
                                                const unsigned short* __restrict__ W2,
                                                unsigned short* __restrict__ Qo,
                                                unsigned short* __restrict__ Ko,
                                                unsigned short* __restrict__ Vto) {
  __shared__ __align__(16) unsigned short lsA[128 * 64];
  __shared__ __align__(16) unsigned short lsB[128 * 64];
  const int tid = threadIdx.x;
  const int lane = tid & 63, wave = tid >> 6;
  const int l31 = lane & 31, half = lane >> 5;
  const int wr = wave >> 1, wc = wave & 1;
  const int bm = blockIdx.x;
  const int which = blockIdx.y >> 4;
  const int bn = blockIdx.y & 15;

  f32x16 acc[2][2];
#pragma unroll
  for (int i = 0; i < 2; i++)
#pragma unroll
    for (int j = 0; j < 2; j++)
#pragma unroll
      for (int r = 0; r < 16; r++) acc[i][j][r] = 0.f;

  if (which < 2) {
    const unsigned short* W = (which == 0) ? W0 : W1;
    unsigned short* outp = (which == 0) ? Qo : Ko;
    gemm_core32(A + (size_t)bm * 128 * HC, W + (size_t)bn * 128 * HC, lsA, lsB, acc, tid);
    // epilogue with fused RoPE: d_lo = wc*32+l31 (nj=0), d_hi = d_lo+64 (nj=1)
    const int dlo = wc * 32 + l31;
    const float invf = __expf((float)dlo * (-0.14391156831212787f));
    const int h = bn;
#pragma unroll
    for (int mi = 0; mi < 2; mi++)
#pragma unroll
      for (int g = 0; g < 4; g++)
#pragma unroll
        for (int rr = 0; rr < 4; rr++) {
          int m = bm * 128 + wr * 64 + mi * 32 + rr + 8 * g + 4 * half;
          int t = m & 255, b = m >> 8;
          float ang = (float)t * invf;
          float sn, cs;
          __sincosf(ang, &sn, &cs);
          int reg = g * 4 + rr;
          float lo = acc[mi][0][reg], hi = acc[mi][1][reg];
          size_t base = (((size_t)b * HH + h) * HT + t) * HD;
          outp[base + dlo] = f2bf(lo * cs - hi * sn);
          outp[base + 64 + dlo] = f2bf(hi * cs + lo * sn);
        }
  } else {
    // V^T: A-operand = wv tile, B-operand = x tile; output rows = channels (h,d)
    gemm_core32(W2 + (size_t)bn * 128 * HC, A + (size_t)bm * 128 * HC, lsA, lsB, acc, tid);
    const int h = bn;
#pragma unroll
    for (int mi = 0; mi < 2; mi++)
#pragma unroll
      for (int nj = 0; nj < 2; nj++)
#pragma unroll
        for (int g = 0; g < 4; g++)
#pragma unroll
          for (int rr = 0; rr < 4; rr++) {
            int d = wr * 64 + mi * 32 + rr + 8 * g + 4 * half;
            int np = bm * 128 + nj * 64 + wc * 32 + l31;
            int b = np >> 8, t = np & 255;
            Vto[(((size_t)b * HH + h) * HD + d) * HT + t] = f2bf(acc[mi][nj][g * 4 + rr]);
          }
  }
}

// ---------------- causal flash attention ----------------
// Block = 4 waves; block handles 64 q-rows of one (b,h); wave owns 16 q-rows.
// Q,K in [B,H,T,D] (pre-RoPEd), Vt in [B,H,D,T]. Y written as [B,T,C] bf16.
// NOTE: no min-waves bound — at R1-R3 __launch_bounds__(256,4) capped VGPR at 128,
// below this kernel's ~130-160 natural pressure -> scratch spills in the softmax
// serial chain (suspected ~170us hidden cost). Let the allocator breathe.
__global__ __launch_bounds__(256) void attn_kernel(const unsigned short* __restrict__ Q,
                                                   const unsigned short* __restrict__ K,
                                                   const unsigned short* __restrict__ Vt,
                                                   unsigned short* __restrict__ Y) {
  const int g = blockIdx.x;
  const int wq = 3 - (g >> 9);
  const int bh = g & 511;
  const int wave = threadIdx.x >> 6;
  const int lane = threadIdx.x & 63;
  const int quad = lane >> 4, l16 = lane & 15;

  const unsigned short* Qh = Q + (size_t)bh * HT * HD;
  const unsigned short* Kh = K + (size_t)bh * HT * HD;
  const unsigned short* Vh = Vt + (size_t)bh * HD * HT;

  __shared__ __align__(16) unsigned short P[4][16 * 72];
  unsigned short* Pw = P[wave];

  const int qrow = wq * 64 + wave * 16;

  bf16x8 qf[4];
#pragma unroll
  for (int ks = 0; ks < 4; ks++)
    qf[ks] = *(const bf16x8*)(Qh + (size_t)(qrow + l16) * HD + ks * 32 + quad * 8);

  f32x4 o[8];
#pragma unroll
  for (int di = 0; di < 8; di++) o[di] = f32x4{0.f, 0.f, 0.f, 0.f};
  float mrow[4], lrow[4];
#pragma unroll
  for (int r = 0; r < 4; r++) { mrow[r] = -1e30f; lrow[r] = 0.f; }

  const float scale = 0.088388347648318447f;  // 1/sqrt(128)

  for (int ct = 0; ct <= wq; ++ct) {
    f32x4 s[4];
#pragma unroll
    for (int ni = 0; ni < 4; ni++) s[ni] = f32x4{0.f, 0.f, 0.f, 0.f};
    const int nimax = (ct == wq) ? wave : 3;
#pragma unroll
    for (int ks = 0; ks < 4; ks++) {
#pragma unroll
      for (int ni = 0; ni < 4; ni++) {
        if (ni <= nimax) {
          bf16x8 kf = *(const bf16x8*)(Kh + (size_t)(ct * 64 + ni * 16 + l16) * HD + ks * 32 + quad * 8);
          s[ni] = __builtin_amdgcn_mfma_f32_16x16x32_bf16(qf[ks], kf, s[ni], 0, 0, 0);
        }
      }
    }
    if (ct == wq) {
#pragma unroll
      for (int ni = 0; ni < 4; ni++)
#pragma unroll
        for (int r = 0; r < 4; r++) {
          int qr = wave * 16 + quad * 4 + r;
          int kc = ni * 16 + l16;
          s[ni][r] = (kc <= qr) ? s[ni][r] * scale : -1e30f;
        }
    } else {
#pragma unroll
      for (int ni = 0; ni < 4; ni++)
#pragma unroll
        for (int r = 0; r < 4; r++) s[ni][r] *= scale;
    }
#pragma unroll
    for (int r = 0; r < 4; r++) {
      float v = fmaxf(fmaxf(s[0][r], s[1][r]), fmaxf(s[2][r], s[3][r]));
      v = fmaxf(v, __shfl_xor(v, 1, 64));
      v = fmaxf(v, __shfl_xor(v, 2, 64));
      v = fmaxf(v, __shfl_xor(v, 4, 64));
      v = fmaxf(v, __shfl_xor(v, 8, 64));
      float mnew = fmaxf(mrow[r], v);
      float alpha = __expf(mrow[r] - mnew);
      mrow[r] = mnew;
      float rs = 0.f;
#pragma unroll
      for (int ni = 0; ni < 4; ni++) {
        float e = __expf(s[ni][r] - mnew);
        s[ni][r] = e;
        rs += e;
      }
      rs += __shfl_xor(rs, 1, 64);
      rs += __shfl_xor(rs, 2, 64);
      rs += __shfl_xor(rs, 4, 64);
      rs += __shfl_xor(rs, 8, 64);
      lrow[r] = lrow[r] * alpha + rs;
#pragma unroll
      for (int di = 0; di < 8; di++) o[di][r] *= alpha;
    }
#pragma unroll
    for (int ni = 0; ni < 4; ni++)
#pragma unroll
      for (int r = 0; r < 4; r++)
        Pw[(quad * 4 + r) * 72 + ni * 16 + l16] = f2bf(s[ni][r]);
#pragma unroll
    for (int ks = 0; ks < 2; ks++) {
      bf16x8 pf = *(const bf16x8*)(Pw + (size_t)l16 * 72 + ks * 32 + quad * 8);
#pragma unroll
      for (int di = 0; di < 8; di++) {
        bf16x8 vf = *(const bf16x8*)(Vh + (size_t)(di * 16 + l16) * HT + ct * 64 + ks * 32 + quad * 8);
        o[di] = __builtin_amdgcn_mfma_f32_16x16x32_bf16(pf, vf, o[di], 0, 0, 0);
      }
    }
  }

  const int b = bh >> 4, h = bh & 15;
#pragma unroll
  for (int r = 0; r < 4; r++) {
    float inv = 1.f / lrow[r];
    int t = qrow + quad * 4 + r;
    size_t rowb = ((size_t)b * HT + t) * HC + h * HD;
#pragma unroll
    for (int di = 0; di < 8; di++)
      Y[rowb + di * 16 + l16] = f2bf(o[di][r] * inv);
  }
}

// ---------------- launch ----------------
extern "C" void kernel_launch(void* const* d_in, const int* in_sizes, int n_in,
                              void* d_out, int out_size, void* d_ws, size_t ws_size,
                              hipStream_t stream) {
  const float* x  = (const float*)d_in[0];
  const float* wq = (const float*)d_in[1];
  const float* wk = (const float*)d_in[2];
  const float* wv = (const float*)d_in[3];
  const float* wo = (const float*)d_in[4];
  float* out = (float*)d_out;

  char* ws = (char*)d_ws;
  const size_t MB = (size_t)1 << 20;
  unsigned short* wqb = (unsigned short*)(ws + 0 * MB);
  unsigned short* wkb = (unsigned short*)(ws + 8 * MB);
  unsigned short* wvb = (unsigned short*)(ws + 16 * MB);
  unsigned short* wob = (unsigned short*)(ws + 24 * MB);
  unsigned short* xb  = (unsigned short*)(ws + 32 * MB);
  unsigned short* Qb  = (unsigned short*)(ws + 64 * MB);
  unsigned short* Kb  = (unsigned short*)(ws + 96 * MB);
  unsigned short* Vtb = (unsigned short*)(ws + 128 * MB);
  unsigned short* Yb  = xb;  // reuse x's bf16 buffer after QKV GEMMs

  cvt_all<<<32768, 256, 0, stream>>>(x, wq, wk, wv, wo, xb, wqb, wkb, wvb, wob);

  gemm_qkv<<<dim3(HM / 128, 48), 256, 0, stream>>>(xb, wqb, wkb, wvb, Qb, Kb, Vtb);

  attn_kernel<<<2048, 256, 0, stream>>>(Qb, Kb, Vtb, Yb);

  gemm_out<<<dim3(HM / 128, HC / 128), 256, 0, stream>>>(Yb, wob, out);
}

// Round 5
// 511.256 us; speedup vs baseline: 1.0673x; 1.0673x over previous
//
#include <hip/hip_runtime.h>

#define HB 32
#define HT 256
#define HC 2048
#define HH 16
#define HD 128
#define HM (HB * HT)  // 8192

typedef __bf16 bf16x8 __attribute__((ext_vector_type(8)));
typedef float f32x4 __attribute__((ext_vector_type(4)));
typedef float f32x16 __attribute__((ext_vector_type(16)));

__device__ __forceinline__ unsigned short f2bf(float f) {
  unsigned u = __float_as_uint(f);
  u += 0x7FFFu + ((u >> 16) & 1u);  // round-to-nearest-even
  return (unsigned short)(u >> 16);
}
__device__ __forceinline__ float bf2f(unsigned short h) {
  return __uint_as_float(((unsigned)h) << 16);
}

// ---------------- fused fp32 -> bf16 convert (x + 4 weights) ----------------
__global__ __launch_bounds__(256) void cvt_all(
    const float* __restrict__ x, const float* __restrict__ wq, const float* __restrict__ wk,
    const float* __restrict__ wv, const float* __restrict__ wo,
    unsigned short* __restrict__ xb, unsigned short* __restrict__ wqb,
    unsigned short* __restrict__ wkb, unsigned short* __restrict__ wvb,
    unsigned short* __restrict__ wob) {
  size_t i = (size_t)blockIdx.x * 256 + threadIdx.x;
  const float* src;
  unsigned short* dst;
  size_t off;
  if (i < 4194304) {
    src = x; dst = xb; off = i;
  } else {
    size_t j = i - 4194304;
    int w = (int)(j >> 20);
    off = j & 1048575;
    src = (w == 0) ? wq : (w == 1) ? wk : (w == 2) ? wv : wo;
    dst = (w == 0) ? wqb : (w == 1) ? wkb : (w == 2) ? wvb : wob;
  }
  float4 v = ((const float4*)src)[off];
  ushort4 o;
  o.x = f2bf(v.x); o.y = f2bf(v.y); o.z = f2bf(v.z); o.w = f2bf(v.w);
  ((ushort4*)dst)[off] = o;
}

// ---------------- GEMM core: 128x256 block tile, BK=64, 32x32x16 MFMA ----------------
// Per wave: 64x128 output (mi 0..1 x nj 0..3). 43 FLOP per LDS byte read
// (vs 32 for 64x64/wave) -> LDS-read-bound ceiling rises ~66% -> ~88% MFMA.
__device__ __forceinline__ void gl_lds16(const unsigned short* g, unsigned short* l) {
  __builtin_amdgcn_global_load_lds((const __attribute__((address_space(1))) void*)g,
                                   (__attribute__((address_space(3))) void*)l, 16, 0, 0);
}

__device__ __forceinline__ void gemm_core_wide(const unsigned short* __restrict__ Ab,
                                               const unsigned short* __restrict__ Wb,
                                               unsigned short* lsA, unsigned short* lsB,
                                               f32x16 acc[2][4], int tid) {
  const int lane = tid & 63, wave = tid >> 6;
  const int l31 = lane & 31, half = lane >> 5;
  const int wr = wave >> 1, wc = wave & 1;
  for (int kt = 0; kt < HC / 64; ++kt) {
    __syncthreads();
    // stage A: 128 rows x 8 chunks, XOR swizzle cc -> cc ^ (row&7)
#pragma unroll
    for (int i = 0; i < 4; i++) {
      int c = i * 256 + tid;
      int row = c >> 3, cc = c & 7;
      int gc = cc ^ (row & 7);
      gl_lds16(Ab + (size_t)row * HC + kt * 64 + gc * 8, lsA + c * 8);
    }
    // stage B: 256 rows x 8 chunks
#pragma unroll
    for (int i = 0; i < 8; i++) {
      int c = i * 256 + tid;
      int row = c >> 3, cc = c & 7;
      int gc = cc ^ (row & 7);
      gl_lds16(Wb + (size_t)row * HC + kt * 64 + gc * 8, lsB + c * 8);
    }
    __syncthreads();
#pragma unroll
    for (int ks = 0; ks < 4; ++ks) {
      const int g = ks * 2 + half;
      bf16x8 af[2], bfr[4];
#pragma unroll
      for (int mi = 0; mi < 2; mi++) {
        int r = wr * 64 + mi * 32 + l31;
        int cc = g ^ (r & 7);
        af[mi] = *(const bf16x8*)(lsA + r * 64 + cc * 8);
      }
#pragma unroll
      for (int nj = 0; nj < 4; nj++) {
        int r = wc * 128 + nj * 32 + l31;
        int cc = g ^ (r & 7);
        bfr[nj] = *(const bf16x8*)(lsB + r * 64 + cc * 8);
      }
#pragma unroll
      for (int mi = 0; mi < 2; mi++)
#pragma unroll
        for (int nj = 0; nj < 4; nj++)
          acc[mi][nj] = __builtin_amdgcn_mfma_f32_32x32x16_bf16(af[mi], bfr[nj], acc[mi][nj], 0, 0, 0);
    }
  }
}

// Output projection GEMM: fp32 out [M, 2048]; grid (64, 8)
__global__ __launch_bounds__(256, 2) void gemm_out(const unsigned short* __restrict__ A,
                                                   const unsigned short* __restrict__ W,
                                                   float* __restrict__ outp) {
  __shared__ __align__(16) unsigned short lsA[128 * 64];
  __shared__ __align__(16) unsigned short lsB[256 * 64];
  const int tid = threadIdx.x;
  const int lane = tid & 63, wave = tid >> 6;
  const int l31 = lane & 31, half = lane >> 5;
  const int wr = wave >> 1, wc = wave & 1;
  const int bm = blockIdx.x, bn = blockIdx.y;

  f32x16 acc[2][4];
#pragma unroll
  for (int i = 0; i < 2; i++)
#pragma unroll
    for (int j = 0; j < 4; j++)
#pragma unroll
      for (int r = 0; r < 16; r++) acc[i][j][r] = 0.f;

  gemm_core_wide(A + (size_t)bm * 128 * HC, W + (size_t)bn * 256 * HC, lsA, lsB, acc, tid);

#pragma unroll
  for (int mi = 0; mi < 2; mi++)
#pragma unroll
    for (int nj = 0; nj < 4; nj++)
#pragma unroll
      for (int g = 0; g < 4; g++)
#pragma unroll
        for (int rr = 0; rr < 4; rr++) {
          int m = bm * 128 + wr * 64 + mi * 32 + rr + 8 * g + 4 * half;
          int n = bn * 256 + wc * 128 + nj * 32 + l31;
          outp[(size_t)m * HC + n] = acc[mi][nj][g * 4 + rr];
        }
}

// Fused QKV GEMM: grid (64, 24); blockIdx.y>>3 selects {Q,K,V}.
// Q,K -> [B,H,T,D] with RoPE fused; V -> [B,H,D,T] via operand swap (coalesced).
__global__ __launch_bounds__(256, 2) void gemm_qkv(const unsigned short* __restrict__ A,
                                                    const unsigned short* __restrict__ W0,
                                                    const unsigned short* __restrict__ W1,
                                                    const unsigned short* __restrict__ W2,
                                                    unsigned short* __restrict__ Qo,
                                                    unsigned short* __restrict__ Ko,
                                                    unsigned short* __restrict__ Vto) {
  __shared__ __align__(16) unsigned short lsA[128 * 64];
  __shared__ __align__(16) unsigned short lsB[256 * 64];
  const int tid = threadIdx.x;
  const int lane = tid & 63, wave = tid >> 6;
  const int l31 = lane & 31, half = lane >> 5;
  const int wr = wave >> 1, wc = wave & 1;
  const int bm = blockIdx.x;
  const int which = blockIdx.y >> 3;
  const int bn = blockIdx.y & 7;

  f32x16 acc[2][4];
#pragma unroll
  for (int i = 0; i < 2; i++)
#pragma unroll
    for (int j = 0; j < 4; j++)
#pragma unroll
      for (int r = 0; r < 16; r++) acc[i][j][r] = 0.f;

  if (which < 2) {
    const unsigned short* W = (which == 0) ? W0 : W1;
    unsigned short* outp = (which == 0) ? Qo : Ko;
    gemm_core_wide(A + (size_t)bm * 128 * HC, W + (size_t)bn * 256 * HC, lsA, lsB, acc, tid);
    // Wave's 128 cols = one head: h = bn*2 + wc. RoPE pair: acc[mi][nj] (d) with
    // acc[mi][nj+2] (d+64), d = nj*32 + l31, nj in {0,1}.
    const int h = bn * 2 + wc;
#pragma unroll
    for (int nj = 0; nj < 2; nj++) {
      const int dlo = nj * 32 + l31;
      const float invf = __expf((float)dlo * (-0.14391156831212787f));
#pragma unroll
      for (int mi = 0; mi < 2; mi++)
#pragma unroll
        for (int g = 0; g < 4; g++)
#pragma unroll
          for (int rr = 0; rr < 4; rr++) {
            int m = bm * 128 + wr * 64 + mi * 32 + rr + 8 * g + 4 * half;
            int t = m & 255, b = m >> 8;
            float ang = (float)t * invf;
            float sn, cs;
            __sincosf(ang, &sn, &cs);
            int reg = g * 4 + rr;
            float lo = acc[mi][nj][reg], hi = acc[mi][nj + 2][reg];
            size_t base = (((size_t)b * HH + h) * HT + t) * HD;
            outp[base + dlo] = f2bf(lo * cs - hi * sn);
            outp[base + 64 + dlo] = f2bf(hi * cs + lo * sn);
          }
    }
  } else {
    // V^T: A-operand = wv channel tile (128 ch = one head), B-operand = x token tile (256).
    int v = bn * 64 + bm;            // 512 blocks
    int tok = v & 31, ch = v >> 5;   // 32 token-tiles x 16 channel-tiles
    gemm_core_wide(W2 + (size_t)ch * 128 * HC, A + (size_t)tok * 256 * HC, lsA, lsB, acc, tid);
    const int b = tok, h = ch;
#pragma unroll
    for (int mi = 0; mi < 2; mi++)
#pragma unroll
      for (int nj = 0; nj < 4; nj++)
#pragma unroll
        for (int g = 0; g < 4; g++)
#pragma unroll
          for (int rr = 0; rr < 4; rr++) {
            int d = wr * 64 + mi * 32 + rr + 8 * g + 4 * half;
            int t = wc * 128 + nj * 32 + l31;
            Vto[(((size_t)b * HH + h) * HD + d) * HT + t] = f2bf(acc[mi][nj][g * 4 + rr]);
          }
  }
}

// ---------------- causal flash attention ----------------
// Block = 4 waves; block handles 64 q-rows of one (b,h); wave owns 16 q-rows.
// Q,K in [B,H,T,D] (pre-RoPEd), Vt in [B,H,D,T]. Y written as [B,T,C] bf16.
__global__ __launch_bounds__(256) void attn_kernel(const unsigned short* __restrict__ Q,
                                                   const unsigned short* __restrict__ K,
                                                   const unsigned short* __restrict__ Vt,
                                                   unsigned short* __restrict__ Y) {
  const int g = blockIdx.x;
  const int wq = 3 - (g >> 9);
  const int bh = g & 511;
  const int wave = threadIdx.x >> 6;
  const int lane = threadIdx.x & 63;
  const int quad = lane >> 4, l16 = lane & 15;

  const unsigned short* Qh = Q + (size_t)bh * HT * HD;
  const unsigned short* Kh = K + (size_t)bh * HT * HD;
  const unsigned short* Vh = Vt + (size_t)bh * HD * HT;

  __shared__ __align__(16) unsigned short P[4][16 * 72];
  unsigned short* Pw = P[wave];

  const int qrow = wq * 64 + wave * 16;

  bf16x8 qf[4];
#pragma unroll
  for (int ks = 0; ks < 4; ks++)
    qf[ks] = *(const bf16x8*)(Qh + (size_t)(qrow + l16) * HD + ks * 32 + quad * 8);

  f32x4 o[8];
#pragma unroll
  for (int di = 0; di < 8; di++) o[di] = f32x4{0.f, 0.f, 0.f, 0.f};
  float mrow[4], lrow[4];
#pragma unroll
  for (int r = 0; r < 4; r++) { mrow[r] = -1e30f; lrow[r] = 0.f; }

  const float scale = 0.088388347648318447f;  // 1/sqrt(128)

  for (int ct = 0; ct <= wq; ++ct) {
    f32x4 s[4];
#pragma unroll
    for (int ni = 0; ni < 4; ni++) s[ni] = f32x4{0.f, 0.f, 0.f, 0.f};
    const int nimax = (ct == wq) ? wave : 3;
#pragma unroll
    for (int ks = 0; ks < 4; ks++) {
#pragma unroll
      for (int ni = 0; ni < 4; ni++) {
        if (ni <= nimax) {
          bf16x8 kf = *(const bf16x8*)(Kh + (size_t)(ct * 64 + ni * 16 + l16) * HD + ks * 32 + quad * 8);
          s[ni] = __builtin_amdgcn_mfma_f32_16x16x32_bf16(qf[ks], kf, s[ni], 0, 0, 0);
        }
      }
    }
    if (ct == wq) {
#pragma unroll
      for (int ni = 0; ni < 4; ni++)
#pragma unroll
        for (int r = 0; r < 4; r++) {
          int qr = wave * 16 + quad * 4 + r;
          int kc = ni * 16 + l16;
          s[ni][r] = (kc <= qr) ? s[ni][r] * scale : -1e30f;
        }
    } else {
#pragma unroll
      for (int ni = 0; ni < 4; ni++)
#pragma unroll
        for (int r = 0; r < 4; r++) s[ni][r] *= scale;
    }
#pragma unroll
    for (int r = 0; r < 4; r++) {
      float v = fmaxf(fmaxf(s[0][r], s[1][r]), fmaxf(s[2][r], s[3][r]));
      v = fmaxf(v, __shfl_xor(v, 1, 64));
      v = fmaxf(v, __shfl_xor(v, 2, 64));
      v = fmaxf(v, __shfl_xor(v, 4, 64));
      v = fmaxf(v, __shfl_xor(v, 8, 64));
      float mnew = fmaxf(mrow[r], v);
      float alpha = __expf(mrow[r] - mnew);
      mrow[r] = mnew;
      float rs = 0.f;
#pragma unroll
      for (int ni = 0; ni < 4; ni++) {
        float e = __expf(s[ni][r] - mnew);
        s[ni][r] = e;
        rs += e;
      }
      rs += __shfl_xor(rs, 1, 64);
      rs += __shfl_xor(rs, 2, 64);
      rs += __shfl_xor(rs, 4, 64);
      rs += __shfl_xor(rs, 8, 64);
      lrow[r] = lrow[r] * alpha + rs;
#pragma unroll
      for (int di = 0; di < 8; di++) o[di][r] *= alpha;
    }
#pragma unroll
    for (int ni = 0; ni < 4; ni++)
#pragma unroll
      for (int r = 0; r < 4; r++)
        Pw[(quad * 4 + r) * 72 + ni * 16 + l16] = f2bf(s[ni][r]);
#pragma unroll
    for (int ks = 0; ks < 2; ks++) {
      bf16x8 pf = *(const bf16x8*)(Pw + (size_t)l16 * 72 + ks * 32 + quad * 8);
#pragma unroll
      for (int di = 0; di < 8; di++) {
        bf16x8 vf = *(const bf16x8*)(Vh + (size_t)(di * 16 + l16) * HT + ct * 64 + ks * 32 + quad * 8);
        o[di] = __builtin_amdgcn_mfma_f32_16x16x32_bf16(pf, vf, o[di], 0, 0, 0);
      }
    }
  }

  const int b = bh >> 4, h = bh & 15;
#pragma unroll
  for (int r = 0; r < 4; r++) {
    float inv = 1.f / lrow[r];
    int t = qrow + quad * 4 + r;
    size_t rowb = ((size_t)b * HT + t) * HC + h * HD;
#pragma unroll
    for (int di = 0; di < 8; di++)
      Y[rowb + di * 16 + l16] = f2bf(o[di][r] * inv);
  }
}

// ---------------- launch ----------------
extern "C" void kernel_launch(void* const* d_in, const int* in_sizes, int n_in,
                              void* d_out, int out_size, void* d_ws, size_t ws_size,
                              hipStream_t stream) {
  const float* x  = (const float*)d_in[0];
  const float* wq = (const float*)d_in[1];
  const float* wk = (const float*)d_in[2];
  const float* wv = (const float*)d_in[3];
  const float* wo = (const float*)d_in[4];
  float* out = (float*)d_out;

  char* ws = (char*)d_ws;
  const size_t MB = (size_t)1 << 20;
  unsigned short* wqb = (unsigned short*)(ws + 0 * MB);
  unsigned short* wkb = (unsigned short*)(ws + 8 * MB);
  unsigned short* wvb = (unsigned short*)(ws + 16 * MB);
  unsigned short* wob = (unsigned short*)(ws + 24 * MB);
  unsigned short* xb  = (unsigned short*)(ws + 32 * MB);
  unsigned short* Qb  = (unsigned short*)(ws + 64 * MB);
  unsigned short* Kb  = (unsigned short*)(ws + 96 * MB);
  unsigned short* Vtb = (unsigned short*)(ws + 128 * MB);
  unsigned short* Yb  = xb;  // reuse x's bf16 buffer after QKV GEMMs

  cvt_all<<<32768, 256, 0, stream>>>(x, wq, wk, wv, wo, xb, wqb, wkb, wvb, wob);

  gemm_qkv<<<dim3(HM / 128, 24), 256, 0, stream>>>(xb, wqb, wkb, wvb, Qb, Kb, Vtb);

  attn_kernel<<<2048, 256, 0, stream>>>(Qb, Kb, Vtb, Yb);

  gemm_out<<<dim3(HM / 128, HC / 256), 256, 0, stream>>>(Yb, wob, out);
}